// Round 11
// baseline (207.567 us; speedup 1.0000x reference)
//
#include <hip/hip_runtime.h>

#define B_ 4
#define T_ 512
#define C_ 128
#define NEG_INF_ (-1e22f)

// ---------------------------------------------------------------------------
// Kernel 1: q = x @ WQ, k = x @ WK (row-major (B*T, C)).
// grid 512 blocks x 256 threads, 4 rows/block -> 2 blocks/CU, 8 waves/CU.
// No W staging: W[c][d] has zero intra-block reuse (one thread per (m,d)),
// so columns stream from L1/L2, coalesced across lanes. x rows broadcast
// from a 2 KB LDS tile.
// ---------------------------------------------------------------------------
__global__ __launch_bounds__(256) void qk_gemm(const float* __restrict__ x,
                                               const float* __restrict__ WQ,
                                               const float* __restrict__ WK,
                                               float* __restrict__ q,
                                               float* __restrict__ k) {
    __shared__ float xs[C_][4];        // [c][r] interleaved, 2 KB
    const int tid = threadIdx.x;
    const size_t rowbase = (size_t)blockIdx.x * 4 * C_;

    #pragma unroll
    for (int e = 0; e < 2; ++e) {
        int idx = e * 256 + tid;       // 0..511
        xs[idx & 127][idx >> 7] = x[rowbase + idx];
    }
    __syncthreads();

    const int m = tid >> 7;            // 0=Q 1=K (wave-uniform)
    const int d = tid & 127;
    const float* __restrict__ W = m ? WK : WQ;
    float a0 = 0.f, a1 = 0.f, a2 = 0.f, a3 = 0.f;
    #pragma unroll 8
    for (int c = 0; c < C_; ++c) {
        float w = W[c * C_ + d];                       // lanes stride-1
        float4 xv = *(const float4*)&xs[c][0];         // uniform broadcast
        a0 += xv.x * w; a1 += xv.y * w; a2 += xv.z * w; a3 += xv.w * w;
    }
    float* o = m ? k : q;
    o[rowbase + d]           = a0;
    o[rowbase + C_ + d]      = a1;
    o[rowbase + 2 * C_ + d]  = a2;
    o[rowbase + 3 * C_ + d]  = a3;
}

// ---------------------------------------------------------------------------
// Kernel 2: fused score + mask + softmax + PV.
// grid = B*(T/4) = 512 blocks x 512 threads (8 waves). LDS ~67 KB -> 2
// blocks/CU (16 waves/CU) PROVIDED VGPR <= 128.
// NOTE (r8 post-mortem): __launch_bounds__(512, 4) made LLVM cap VGPR at 64
// -> ~100 spill slots/thread -> 200 MB scratch traffic -> 77 us. Plain
// __launch_bounds__(512) (r2 precedent: 164 VGPR, no spill) lets the
// allocator size naturally; LDS supplies the occupancy floor.
// Block owns 4 i-rows; thread owns ONE j (= tid) for all 4 rows, so each
// swizzled qv b128 read feeds 16 FMAs.
// q[b] staged per 32-d chunk in LDS [512 j][32 d], slot ^= (j&7) XOR swizzle:
// staging writes and reads both at the 8-words/bank b128 floor.
// Softmax: wave shfl_xor over 64 j + 8-wave LDS combine.
// PV: att in regs, readlane broadcast; partials into the DEAD qs buffer.
// ---------------------------------------------------------------------------
__global__ __launch_bounds__(512) void lgcn_att(const float* __restrict__ x,
                                                const float* __restrict__ adj,
                                                const float* __restrict__ q,
                                                const float* __restrict__ k,
                                                const float* __restrict__ p,
                                                float* __restrict__ out) {
    __shared__ float qs[512 * 32];     // 64 KB; reused as outp[8][4][C_] later
    __shared__ float ks[4][C_];        // 2 KB
    __shared__ float ps[C_];           // 0.5 KB
    __shared__ float redm[8][4];
    __shared__ float reds[8][4];

    const int tid  = threadIdx.x;
    const int bid  = blockIdx.x;
    const int b    = bid >> 7;          // 4 b x 128 row-groups
    const int i0   = (bid & 127) << 2;  // 4 rows
    const int wv   = tid >> 6;          // 0..7
    const int lane = tid & 63;
    const int j    = tid;               // this thread's column, 0..511

    // stage k rows (4 x 128, one elem/thread) and p
    ks[tid >> 7][tid & 127] =
        k[((size_t)b * T_ + i0 + (tid >> 7)) * C_ + (tid & 127)];
    if (tid < C_) ps[tid] = p[tid];

    float s4[4] = {0.f, 0.f, 0.f, 0.f};
    const float* qb = q + (size_t)b * T_ * C_;

    for (int cd = 0; cd < 4; ++cd) {
        __syncthreads();               // qs reuse + (cd==0) ks/ps commit
        // stage q chunk: 512 j x 32 d = 4096 float4, 8 per thread
        #pragma unroll
        for (int it = 0; it < 8; ++it) {
            int idx = it * 512 + tid;
            int jj = idx >> 3, sl = idx & 7;
            float4 v = *(const float4*)&qb[(size_t)jj * C_ + cd * 32 + sl * 4];
            int off = jj * 128 + ((sl ^ (jj & 7)) << 4);   // bytes
            *(float4*)((char*)qs + off) = v;
        }
        __syncthreads();

        #pragma unroll
        for (int dl8 = 0; dl8 < 8; ++dl8) {
            int off = j * 128 + ((dl8 ^ (j & 7)) << 4);
            float4 qv = *(const float4*)((char*)qs + off);     // per-lane
            float4 pv = *(const float4*)&ps[cd * 32 + dl8 * 4]; // broadcast
            #pragma unroll
            for (int r = 0; r < 4; ++r) {
                float4 kv = *(const float4*)&ks[r][cd * 32 + dl8 * 4]; // bcast
                s4[r] += pv.x * fmaxf(qv.x + kv.x, 0.f)
                       + pv.y * fmaxf(qv.y + kv.y, 0.f)
                       + pv.z * fmaxf(qv.z + kv.z, 0.f)
                       + pv.w * fmaxf(qv.w + kv.w, 0.f);
            }
        }
    }

    // mask (exact -1e22 replacement == ref's add in fp32: masked exp -> 0)
    const float* adjb = adj + ((size_t)b * T_ + i0) * T_;
    #pragma unroll
    for (int r = 0; r < 4; ++r) {
        float a = adjb[(size_t)r * T_ + j];
        s4[r] = (a > 0.f) ? s4[r] : NEG_INF_;
    }

    // row max: wave reduce over its 64 j, then 8-wave LDS combine
    #pragma unroll
    for (int r = 0; r < 4; ++r) {
        float mv = s4[r];
        #pragma unroll
        for (int o = 32; o > 0; o >>= 1)
            mv = fmaxf(mv, __shfl_xor(mv, o, 64));
        if (lane == 0) redm[wv][r] = mv;
    }
    __syncthreads();                   // also: all qs score reads done
    float e4[4];
    #pragma unroll
    for (int r = 0; r < 4; ++r) {
        float rowmax = fmaxf(
            fmaxf(fmaxf(redm[0][r], redm[1][r]), fmaxf(redm[2][r], redm[3][r])),
            fmaxf(fmaxf(redm[4][r], redm[5][r]), fmaxf(redm[6][r], redm[7][r])));
        float ev = __expf(s4[r] - rowmax);
        e4[r] = ev;
        float sm = ev;
        #pragma unroll
        for (int o = 32; o > 0; o >>= 1)
            sm += __shfl_xor(sm, o, 64);
        if (lane == 0) reds[wv][r] = sm;
    }

    // PV: wave covers j in [wv*64, wv*64+64); att broadcast via readlane;
    // lane owns d-pair {2*lane, 2*lane+1}. Partials into aliased qs.
    float* outp = qs;                  // [8][4][C_] floats = 16 KB
    const float2* xb2 = (const float2*)(x + (size_t)b * T_ * C_);
    float2 acc[4];
    #pragma unroll
    for (int r = 0; r < 4; ++r) acc[r] = make_float2(0.f, 0.f);
    const int jbase = wv * 64;
    #pragma unroll 4
    for (int l = 0; l < 64; ++l) {
        float2 xv = xb2[(size_t)(jbase + l) * 64 + lane];   // 512B coalesced
        #pragma unroll
        for (int r = 0; r < 4; ++r) {
            float a = __int_as_float(
                __builtin_amdgcn_readlane(__float_as_int(e4[r]), l));
            acc[r].x += a * xv.x;
            acc[r].y += a * xv.y;
        }
    }
    __syncthreads();                   // reds committed; qs reads long done
    #pragma unroll
    for (int r = 0; r < 4; ++r)
        *(float2*)&outp[(wv * 4 + r) * C_ + lane * 2] = acc[r];
    __syncthreads();

    // combine 8 waves' partials, normalize, write (row = tid>>7, d = tid&127)
    {
        const int row = tid >> 7;      // 0..3
        const int d   = tid & 127;
        float v = 0.f;
        #pragma unroll
        for (int w = 0; w < 8; ++w)
            v += outp[(w * 4 + row) * C_ + d];
        float denom = 0.f;
        #pragma unroll
        for (int w = 0; w < 8; ++w)
            denom += reds[w][row];     // LDS, runtime row: fine
        out[((size_t)b * T_ + i0 + row) * C_ + d] = v / denom;
    }
}

extern "C" void kernel_launch(void* const* d_in, const int* in_sizes, int n_in,
                              void* d_out, int out_size, void* d_ws, size_t ws_size,
                              hipStream_t stream) {
    const float* x   = (const float*)d_in[0];
    const float* adj = (const float*)d_in[1];
    const float* WQ  = (const float*)d_in[2];
    const float* WK  = (const float*)d_in[3];
    const float* p   = (const float*)d_in[4];
    float* outp = (float*)d_out;

    float* q = (float*)d_ws;                       // 1 MB
    float* k = q + (size_t)B_ * T_ * C_;           // 1 MB
    (void)ws_size; (void)in_sizes; (void)n_in;

    qk_gemm<<<512, 256, 0, stream>>>(x, WQ, WK, q, k);
    lgcn_att<<<512, 512, 0, stream>>>(x, adj, q, k, p, outp);
}

// Round 12
// 96.135 us; speedup vs baseline: 2.1591x; 2.1591x over previous
//
#include <hip/hip_runtime.h>

#define B_ 4
#define T_ 512
#define C_ 128
#define NEG_INF_ (-1e22f)
#define QSTRIDE 20   // 16 data floats + 4 pad: 80 B row stride, 16B-aligned,
                     // gcd(20,32)=4 -> b128 reads/writes at 8-words/bank floor

// ---------------------------------------------------------------------------
// Kernel 1: q = x @ WQ, k = x @ WK (row-major (B*T, C)). Unchanged from r3.
// 512 blocks x 256 thr, 4 rows/block. W streams from L2 (zero intra-block
// reuse), x broadcast from 2 KB LDS.
// ---------------------------------------------------------------------------
__global__ __launch_bounds__(256) void qk_gemm(const float* __restrict__ x,
                                               const float* __restrict__ WQ,
                                               const float* __restrict__ WK,
                                               float* __restrict__ q,
                                               float* __restrict__ k) {
    __shared__ float xs[C_][4];        // [c][r] interleaved, 2 KB
    const int tid = threadIdx.x;
    const size_t rowbase = (size_t)blockIdx.x * 4 * C_;

    #pragma unroll
    for (int e = 0; e < 2; ++e) {
        int idx = e * 256 + tid;       // 0..511
        xs[idx & 127][idx >> 7] = x[rowbase + idx];
    }
    __syncthreads();

    const int m = tid >> 7;            // 0=Q 1=K (wave-uniform)
    const int d = tid & 127;
    const float* __restrict__ W = m ? WK : WQ;
    float a0 = 0.f, a1 = 0.f, a2 = 0.f, a3 = 0.f;
    #pragma unroll 8
    for (int c = 0; c < C_; ++c) {
        float w = W[c * C_ + d];                       // lanes stride-1
        float4 xv = *(const float4*)&xs[c][0];         // uniform broadcast
        a0 += xv.x * w; a1 += xv.y * w; a2 += xv.z * w; a3 += xv.w * w;
    }
    float* o = m ? k : q;
    o[rowbase + d]           = a0;
    o[rowbase + C_ + d]      = a1;
    o[rowbase + 2 * C_ + d]  = a2;
    o[rowbase + 3 * C_ + d]  = a3;
}

// ---------------------------------------------------------------------------
// Kernel 2: fused score + mask + softmax + PV.
// r11 post-mortem: 512-thr blocks force a <=128 VGPR cap (r8: 64, r11: 128)
// and this kernel's natural live state is ~160 (r2) -> unavoidable spill
// (184 MB scratch writes, 149 us). FIX: 256-thr blocks (4 waves, 1 wave/SIMD
// per block -> no cap; r2 precedent 164 VGPR zero-spill), occupancy from
// 2 blocks/CU via 43.6 KB LDS.
// grid = B*(T/4) = 512 blocks. Block owns 4 i-rows; thread owns j-pair
// {tid, tid+256} for all 4 rows.
// q staged in 8 chunks of [512 j][16 d] at QSTRIDE=20 pad: staging global
// loads coalesced (64B segments), ds writes AND per-lane b128 reads at the
// 8-words/bank floor (gcd(20,32)=4 start-bank spread). No XOR swizzle.
// Softmax: wave shfl_xor (covers the wave's 128 j) + 4-wave LDS combine.
// PV: att in regs, readlane broadcast; partials into dead qs (alias).
// ---------------------------------------------------------------------------
__global__ __launch_bounds__(256) void lgcn_att(const float* __restrict__ x,
                                                const float* __restrict__ adj,
                                                const float* __restrict__ q,
                                                const float* __restrict__ k,
                                                const float* __restrict__ p,
                                                float* __restrict__ out) {
    __shared__ float qs[512 * QSTRIDE];  // 40 KB; later aliased as outp[4][4][C_]
    __shared__ float ks[4][C_];          // 2 KB
    __shared__ float ps[C_];             // 0.5 KB
    __shared__ float redm[4][4];
    __shared__ float reds[4][4];

    const int tid  = threadIdx.x;
    const int bid  = blockIdx.x;
    const int b    = bid >> 7;           // 4 b x 128 row-groups
    const int i0   = (bid & 127) << 2;   // 4 rows
    const int wv   = tid >> 6;           // 0..3
    const int lane = tid & 63;
    const int jA   = tid;                // first owned column
    const int jB   = tid + 256;          // second owned column

    // stage k rows (4 x 128 = 512 elems, 2/thread) and p
    #pragma unroll
    for (int e = 0; e < 2; ++e) {
        int idx = e * 256 + tid;
        ks[idx >> 7][idx & 127] =
            k[((size_t)b * T_ + i0 + (idx >> 7)) * C_ + (idx & 127)];
    }
    if (tid < C_) ps[tid] = p[tid];

    float s4[4][2] = {{0.f, 0.f}, {0.f, 0.f}, {0.f, 0.f}, {0.f, 0.f}};
    const float* qb = q + (size_t)b * T_ * C_;

    for (int cd = 0; cd < 8; ++cd) {
        __syncthreads();               // qs chunk reuse + (cd==0) ks/ps commit
        // stage q chunk: 512 j x 16 d = 2048 float4, 8/thread.
        #pragma unroll
        for (int it = 0; it < 8; ++it) {
            int idx = it * 256 + tid;  // 0..2047
            int jj = idx >> 2, sl = idx & 3;
            float4 v = *(const float4*)&qb[(size_t)jj * C_ + cd * 16 + sl * 4];
            *(float4*)&qs[jj * QSTRIDE + sl * 4] = v;
        }
        __syncthreads();

        #pragma unroll
        for (int dl = 0; dl < 4; ++dl) {
            float4 qvA = *(const float4*)&qs[jA * QSTRIDE + dl * 4];  // per-lane
            float4 qvB = *(const float4*)&qs[jB * QSTRIDE + dl * 4];
            float4 pv  = *(const float4*)&ps[cd * 16 + dl * 4];       // bcast
            #pragma unroll
            for (int r = 0; r < 4; ++r) {
                float4 kv = *(const float4*)&ks[r][cd * 16 + dl * 4]; // bcast
                s4[r][0] += pv.x * fmaxf(qvA.x + kv.x, 0.f)
                          + pv.y * fmaxf(qvA.y + kv.y, 0.f)
                          + pv.z * fmaxf(qvA.z + kv.z, 0.f)
                          + pv.w * fmaxf(qvA.w + kv.w, 0.f);
                s4[r][1] += pv.x * fmaxf(qvB.x + kv.x, 0.f)
                          + pv.y * fmaxf(qvB.y + kv.y, 0.f)
                          + pv.z * fmaxf(qvB.z + kv.z, 0.f)
                          + pv.w * fmaxf(qvB.w + kv.w, 0.f);
            }
        }
    }

    // mask (exact -1e22 replacement == ref's add in fp32: masked exp -> 0)
    const float* adjb = adj + ((size_t)b * T_ + i0) * T_;
    #pragma unroll
    for (int r = 0; r < 4; ++r) {
        float aA = adjb[(size_t)r * T_ + jA];
        float aB = adjb[(size_t)r * T_ + jB];
        s4[r][0] = (aA > 0.f) ? s4[r][0] : NEG_INF_;
        s4[r][1] = (aB > 0.f) ? s4[r][1] : NEG_INF_;
    }

    // row max: wave covers its 128 j (two 64-j halves), 4-wave LDS combine
    #pragma unroll
    for (int r = 0; r < 4; ++r) {
        float mv = fmaxf(s4[r][0], s4[r][1]);
        #pragma unroll
        for (int o = 32; o > 0; o >>= 1)
            mv = fmaxf(mv, __shfl_xor(mv, o, 64));
        if (lane == 0) redm[wv][r] = mv;
    }
    __syncthreads();                   // also: all qs score reads done
    float e4[4][2];
    #pragma unroll
    for (int r = 0; r < 4; ++r) {
        float rowmax = fmaxf(fmaxf(redm[0][r], redm[1][r]),
                             fmaxf(redm[2][r], redm[3][r]));
        e4[r][0] = __expf(s4[r][0] - rowmax);
        e4[r][1] = __expf(s4[r][1] - rowmax);
        float sm = e4[r][0] + e4[r][1];
        #pragma unroll
        for (int o = 32; o > 0; o >>= 1)
            sm += __shfl_xor(sm, o, 64);
        if (lane == 0) reds[wv][r] = sm;
    }

    // PV: wave covers j in [wv*64,+64) and [256+wv*64,+64); readlane bcast;
    // lane owns d-pair. Partials into aliased qs (safe: last qs read was
    // before the barrier above; outp disjoint from redm/reds).
    float* outp = qs;                  // [4][4][C_] = 8 KB alias
    const float2* xb2 = (const float2*)(x + (size_t)b * T_ * C_);
    float2 acc[4];
    #pragma unroll
    for (int r = 0; r < 4; ++r) acc[r] = make_float2(0.f, 0.f);
    const int jbase = wv * 64;
    #pragma unroll 2
    for (int l = 0; l < 64; ++l) {
        float2 xv0 = xb2[(size_t)(jbase + l) * 64 + lane];        // coalesced
        float2 xv1 = xb2[(size_t)(256 + jbase + l) * 64 + lane];
        #pragma unroll
        for (int r = 0; r < 4; ++r) {
            float a0 = __int_as_float(
                __builtin_amdgcn_readlane(__float_as_int(e4[r][0]), l));
            float a1 = __int_as_float(
                __builtin_amdgcn_readlane(__float_as_int(e4[r][1]), l));
            acc[r].x += a0 * xv0.x + a1 * xv1.x;
            acc[r].y += a0 * xv0.y + a1 * xv1.y;
        }
    }
    #pragma unroll
    for (int r = 0; r < 4; ++r)
        *(float2*)&outp[(wv * 4 + r) * C_ + lane * 2] = acc[r];
    __syncthreads();                   // outp + reds visible to all

    // combine 4 waves' partials, normalize, write. 512 outputs, 2/thread.
    #pragma unroll
    for (int e = 0; e < 2; ++e) {
        const int row = (tid >> 7) + e * 2;   // 0..3
        const int d   = tid & 127;
        float v = outp[(0 * 4 + row) * C_ + d] + outp[(1 * 4 + row) * C_ + d]
                + outp[(2 * 4 + row) * C_ + d] + outp[(3 * 4 + row) * C_ + d];
        float denom = reds[0][row] + reds[1][row] + reds[2][row] + reds[3][row];
        out[((size_t)b * T_ + i0 + row) * C_ + d] = v / denom;
    }
}

extern "C" void kernel_launch(void* const* d_in, const int* in_sizes, int n_in,
                              void* d_out, int out_size, void* d_ws, size_t ws_size,
                              hipStream_t stream) {
    const float* x   = (const float*)d_in[0];
    const float* adj = (const float*)d_in[1];
    const float* WQ  = (const float*)d_in[2];
    const float* WK  = (const float*)d_in[3];
    const float* p   = (const float*)d_in[4];
    float* outp = (float*)d_out;

    float* q = (float*)d_ws;                       // 1 MB
    float* k = q + (size_t)B_ * T_ * C_;           // 1 MB
    (void)ws_size; (void)in_sizes; (void)n_in;

    qk_gemm<<<512, 256, 0, stream>>>(x, WQ, WK, q, k);
    lgcn_att<<<512, 256, 0, stream>>>(x, adj, q, k, p, outp);
}